// Round 8
// baseline (752.850 us; speedup 1.0000x reference)
//
#include <hip/hip_runtime.h>
#include <cstdint>
#include <type_traits>

// GNN GATv2 x3 + mean-pool + MLP.
// All three node-transform GEMMs on fp16 MFMA (layer1 K=16 zero-padded to 32).
// fp16 feature tables + fp16 CSR-ordered edge features; CSR segments padded to
// a multiple of 4 with src=-1 markers so the attention kernel runs a clamp-free
// 4-wide software-pipelined loop (R7: VALU-issue-bound at 82%).
constexpr int GNUM = 128;   // graphs

typedef _Float16 h2 __attribute__((ext_vector_type(2)));
typedef _Float16 h4 __attribute__((ext_vector_type(4)));
typedef _Float16 h8 __attribute__((ext_vector_type(8)));
typedef float f4 __attribute__((ext_vector_type(4)));

// ---------------------------------------------------------------- setup kernels

__global__ __launch_bounds__(256) void hist_kernel(const int* __restrict__ dst,
                                                   int* __restrict__ cnt, int E) {
  int i = blockIdx.x * 256 + threadIdx.x;
  if (i < E) atomicAdd(&cnt[dst[i]], 1);
}

// padded row length: (cnt+1) rounded up to multiple of 4 (self loop + pads)
__device__ __forceinline__ int padlen(int c) { return (c + 4) & ~3; }

// ---- 3-phase parallel exclusive scan of padlen(cnt[i]), 512 elems/block ----
__global__ __launch_bounds__(256) void scan_part_kernel(const int* __restrict__ cnt,
                                                        int* __restrict__ bpart, int n) {
  __shared__ int red[256];
  int base = blockIdx.x * 512;
  int t = threadIdx.x;
  int s = 0;
  int i0 = base + t, i1 = base + 256 + t;
  if (i0 < n) s += padlen(cnt[i0]);
  if (i1 < n) s += padlen(cnt[i1]);
  red[t] = s;
  __syncthreads();
  for (int off = 128; off > 0; off >>= 1) {
    if (t < off) red[t] += red[t + off];
    __syncthreads();
  }
  if (t == 0) bpart[blockIdx.x] = red[0];
}

__global__ __launch_bounds__(1024) void scan_top_kernel(const int* __restrict__ bpart,
                                                        int* __restrict__ boff,
                                                        int* __restrict__ row_ptr,
                                                        int B, int n) {
  __shared__ int buf[1024];
  int t = threadIdx.x;
  buf[t] = (t < B) ? bpart[t] : 0;
  __syncthreads();
  for (int off = 1; off < 1024; off <<= 1) {
    int v = (t >= off) ? buf[t - off] : 0;
    __syncthreads();
    buf[t] += v;
    __syncthreads();
  }
  if (t < B) boff[t] = (t == 0) ? 0 : buf[t - 1];
  if (t == 0) row_ptr[n] = buf[1023];
}

__global__ __launch_bounds__(256) void scan_write_kernel(const int* __restrict__ cnt,
                                                         const int* __restrict__ boff,
                                                         int* __restrict__ row_ptr,
                                                         int* __restrict__ fill, int n) {
  __shared__ int red[256];
  int base = blockIdx.x * 512;
  int t = threadIdx.x;
  int i0 = base + 2 * t, i1 = base + 2 * t + 1;
  int v0 = (i0 < n) ? padlen(cnt[i0]) : 0;
  int v1 = (i1 < n) ? padlen(cnt[i1]) : 0;
  int val = v0 + v1;
  red[t] = val;
  __syncthreads();
  for (int off = 1; off < 256; off <<= 1) {
    int u = (t >= off) ? red[t - off] : 0;
    __syncthreads();
    red[t] += u;
    __syncthreads();
  }
  int o = boff[blockIdx.x] + red[t] - val;   // exclusive prefix for this pair
  if (i0 < n) { row_ptr[i0] = o; fill[i0] = o; }
  if (i1 < n) { row_ptr[i1] = o + v0; fill[i1] = o + v0; }
}

// scatter edges into CSR slots; write fp16 edge features directly in CSR order
__global__ __launch_bounds__(256) void scatter_kernel(const int* __restrict__ src,
                                                      const int* __restrict__ dst,
                                                      const float* __restrict__ ea,
                                                      int* __restrict__ fill,
                                                      int* __restrict__ csr_src,
                                                      _Float16* __restrict__ ea_csr, int E) {
  int i = blockIdx.x * 256 + threadIdx.x;
  if (i >= E) return;
  int d = dst[i];
  int p = atomicAdd(&fill[d], 1);
  csr_src[p] = src[i];
  float4 e0 = *(const float4*)&ea[(size_t)i * 8];
  float4 e1 = *(const float4*)&ea[(size_t)i * 8 + 4];
  h8 v;
  v[0] = (_Float16)e0.x; v[1] = (_Float16)e0.y; v[2] = (_Float16)e0.z; v[3] = (_Float16)e0.w;
  v[4] = (_Float16)e1.x; v[5] = (_Float16)e1.y; v[6] = (_Float16)e1.z; v[7] = (_Float16)e1.w;
  *(h8*)&ea_csr[(size_t)p * 8] = v;
}

// fill self-loop slot (at fill[i], i.e. row_start+cnt) with segment-mean attrs;
// mark pad slots with src = -1. 8 threads per node (one per edge channel).
__global__ __launch_bounds__(256) void selfloop_kernel(const int* __restrict__ row_ptr,
                                                       const int* __restrict__ fill,
                                                       int* __restrict__ csr_src,
                                                       _Float16* __restrict__ ea_csr, int n) {
  int idx = blockIdx.x * 256 + threadIdx.x;
  int i = idx >> 3, c = idx & 7;
  if (i >= n) return;
  int s = row_ptr[i], sf = fill[i], e = row_ptr[i + 1];
  float a = 0.f;
  for (int j = s; j < sf; j++) a += (float)ea_csr[(size_t)j * 8 + c];
  float inv = 1.f / fmaxf((float)(sf - s), 1.f);
  ea_csr[(size_t)sf * 8 + c] = (_Float16)(a * inv);
  if (c == 0) {
    csr_src[sf] = i;
    for (int p = sf + 1; p < e; p++) csr_src[p] = -1;
  }
}

// pack w [Kreal][NC] f32 -> fp16 MFMA B-fragment order with zero-padding to Kpad
__global__ __launch_bounds__(256) void pack_kernel(const float* __restrict__ w0,
                                                   _Float16* __restrict__ wp0,
                                                   const float* __restrict__ w1,
                                                   _Float16* __restrict__ wp1,
                                                   int Kreal, int Kpad, int NC) {
  const float* w = blockIdx.y ? w1 : w0;
  _Float16* wp = blockIdx.y ? wp1 : wp0;
  int KB = Kpad / 32;
  int total = (NC / 16) * KB * 64;
  int idx = blockIdx.x * 256 + threadIdx.x;
  if (idx >= total) return;
  int lane = idx & 63;
  int blk = idx >> 6;
  int nt = blk / KB, kb = blk % KB;
  int col = nt * 16 + (lane & 15);
  int krow = kb * 32 + (lane >> 4) * 8;
  h8 v;
#pragma unroll
  for (int j = 0; j < 8; j++)
    v[j] = (krow + j < Kreal) ? (_Float16)w[(size_t)(krow + j) * NC + col] : (_Float16)0.f;
  *(h8*)&wp[(size_t)idx * 8] = v;
}

// f32 -> fp16 convert (vectorized by 4)
__global__ __launch_bounds__(256) void cvt16_kernel(const float* __restrict__ x,
                                                    _Float16* __restrict__ x16, int total4) {
  int i = blockIdx.x * 256 + threadIdx.x;
  if (i >= total4) return;
  float4 v = ((const float4*)x)[i];
  h4 o;
  o[0] = (_Float16)v.x; o[1] = (_Float16)v.y; o[2] = (_Float16)v.z; o[3] = (_Float16)v.w;
  ((h4*)x16)[i] = o;
}

// ---------------------------------------------------------------- node transform GEMMs

// fp16 MFMA, K=128. 256 thr = 4 waves, 16 nodes/wave, 64 nodes/block.
template <int K, int NCOLS>
__global__ __launch_bounds__(256) void k1m_kernel(const _Float16* __restrict__ x,
                                                  const _Float16* __restrict__ wp0,
                                                  const float* __restrict__ b0,
                                                  _Float16* __restrict__ out0,
                                                  const _Float16* __restrict__ wp1,
                                                  const float* __restrict__ b1,
                                                  _Float16* __restrict__ out1, int n) {
  constexpr int NT = NCOLS / 16, KB = K / 32;
  const _Float16* wp = blockIdx.y ? wp1 : wp0;
  const float* b = blockIdx.y ? b1 : b0;
  _Float16* out = blockIdx.y ? out1 : out0;

  int tid = threadIdx.x;
  int wave = tid >> 6, lane = tid & 63;
  int m = lane & 15, quad = lane >> 4;
  int node0 = blockIdx.x * 64 + wave * 16;

  h8 afrag[KB];
  int anode = node0 + m;
  if (anode < n) {
#pragma unroll
    for (int kb = 0; kb < KB; kb++)
      afrag[kb] = *(const h8*)&x[(size_t)anode * K + kb * 32 + quad * 8];
  } else {
#pragma unroll
    for (int kb = 0; kb < KB; kb++) afrag[kb] = (h8)(_Float16)0.f;
  }

  f4 acc[NT] = {};
#pragma unroll
  for (int nt = 0; nt < NT; nt++) {
#pragma unroll
    for (int kb = 0; kb < KB; kb++) {
      h8 bfrag = *(const h8*)&wp[((size_t)(nt * KB + kb) * 64 + lane) * 8];
      acc[nt] = __builtin_amdgcn_mfma_f32_16x16x32_f16(afrag[kb], bfrag, acc[nt], 0, 0, 0);
    }
  }

#pragma unroll
  for (int nt = 0; nt < NT; nt++) {
#pragma unroll
    for (int r = 0; r < 4; r++) {
      int row = node0 + quad * 4 + r;
      if (row < n) {
        int col = nt * 16 + m;
        out[(size_t)row * NCOLS + col] = (_Float16)(acc[nt][r] + b[col]);
      }
    }
  }
}

// fp16 MFMA, Kreal=16 zero-padded to 32 (layer 1). x16 rows of 16 halves.
template <int NCOLS>
__global__ __launch_bounds__(256) void k1m16_kernel(const _Float16* __restrict__ x16,
                                                    const _Float16* __restrict__ wp0,
                                                    const float* __restrict__ b0,
                                                    _Float16* __restrict__ out0,
                                                    const _Float16* __restrict__ wp1,
                                                    const float* __restrict__ b1,
                                                    _Float16* __restrict__ out1, int n) {
  constexpr int NT = NCOLS / 16;
  const _Float16* wp = blockIdx.y ? wp1 : wp0;
  const float* b = blockIdx.y ? b1 : b0;
  _Float16* out = blockIdx.y ? out1 : out0;

  int tid = threadIdx.x;
  int wave = tid >> 6, lane = tid & 63;
  int m = lane & 15, quad = lane >> 4;
  int node0 = blockIdx.x * 64 + wave * 16;

  int anode = node0 + m;
  h8 afrag;
  if (anode < n && quad < 2)
    afrag = *(const h8*)&x16[(size_t)anode * 16 + quad * 8];
  else
    afrag = (h8)(_Float16)0.f;

  f4 acc[NT] = {};
#pragma unroll
  for (int nt = 0; nt < NT; nt++) {
    h8 bfrag = *(const h8*)&wp[((size_t)nt * 64 + lane) * 8];
    acc[nt] = __builtin_amdgcn_mfma_f32_16x16x32_f16(afrag, bfrag, acc[nt], 0, 0, 0);
  }

#pragma unroll
  for (int nt = 0; nt < NT; nt++) {
#pragma unroll
    for (int r = 0; r < 4; r++) {
      int row = node0 + quad * 4 + r;
      if (row < n) {
        int col = nt * 16 + m;
        out[(size_t)row * NCOLS + col] = (_Float16)(acc[nt][r] + b[col]);
      }
    }
  }
}

// ---------------------------------------------------------------- fused GATv2 edge+softmax+aggregate
// One-pass softmax (logits O(1), no max-shift). Segments padded to multiple of
// 4; pad slots have src=-1 -> p forced to 0 (NaN-safe cndmask). 4-wide
// software pipeline: next group's src/ea prefetched before current logits,
// next xl gathers before the shfl-reduce. att pre-scaled by log2(e).
template <int H>
__global__ __launch_bounds__(128) void k2_kernel(
    const _Float16* __restrict__ xl, const _Float16* __restrict__ xr,
    const int* __restrict__ row_ptr, const int* __restrict__ csr_src,
    const _Float16* __restrict__ ea_csr, const float* __restrict__ we,
    const float* __restrict__ att, const float* __restrict__ bc,
    _Float16* __restrict__ out, int n) {
  constexpr int HC = H * 32;
  constexpr int NL = HC / 4;   // lanes per node (32 or 8)
  constexpr int NPB = 128 / NL;

  int tid = threadIdx.x;
  int ln = tid / NL, q = tid % NL;
  int c0 = 4 * q;
  int node = blockIdx.x * NPB + ln;
  if (node >= n) return;

  h2 w2[8][2];
#pragma unroll
  for (int k = 0; k < 8; k++) {
    float4 v = *(const float4*)&we[k * HC + c0];
    w2[k][0] = h2{(_Float16)v.x, (_Float16)v.y};
    w2[k][1] = h2{(_Float16)v.z, (_Float16)v.w};
  }
  const float LOG2E = 1.44269504088896f;
  float4 av = *(const float4*)&att[c0];
  h2 a0 = h2{(_Float16)(av.x * LOG2E), (_Float16)(av.y * LOG2E)};
  h2 a1 = h2{(_Float16)(av.z * LOG2E), (_Float16)(av.w * LOG2E)};
  h4 xrh = *(const h4*)&xr[(size_t)node * HC + c0];
  h2 xr0 = h2{xrh[0], xrh[1]}, xr1 = h2{xrh[2], xrh[3]};
  const h2 p2 = h2{(_Float16)0.2f, (_Float16)0.2f};

  float acc[4] = {0.f, 0.f, 0.f, 0.f};
  float s = 0.f;

  int start = row_ptr[node], end = row_ptr[node + 1];   // len multiple of 4

  int cs[4]; h8 ce[4]; h4 cx[4];
#pragma unroll
  for (int e = 0; e < 4; e++) {
    cs[e] = csr_src[start + e];
    ce[e] = *(const h8*)&ea_csr[(size_t)(start + e) * 8];
  }
#pragma unroll
  for (int e = 0; e < 4; e++) {
    int sx = cs[e] < 0 ? 0 : cs[e];
    cx[e] = *(const h4*)&xl[(size_t)sx * HC + c0];
  }

  for (int j = start; j < end; j += 4) {
    int jn = (j + 4 < end) ? j + 4 : start;   // wrap on last iter (discarded)
    int ns[4]; h8 ne[4]; h4 nx[4];
#pragma unroll
    for (int e = 0; e < 4; e++) {
      ns[e] = csr_src[jn + e];
      ne[e] = *(const h8*)&ea_csr[(size_t)(jn + e) * 8];
    }

    float part[4];
#pragma unroll
    for (int e = 0; e < 4; e++) {
      h2 t0 = h2{cx[e][0], cx[e][1]} + xr0;
      h2 t1 = h2{cx[e][2], cx[e][3]} + xr1;
#pragma unroll
      for (int k = 0; k < 8; k++) {
        h2 ev = h2{ce[e][k], ce[e][k]};
        t0 += ev * w2[k][0];
        t1 += ev * w2[k][1];
      }
      t0 = __builtin_elementwise_max(t0, t0 * p2);
      t1 = __builtin_elementwise_max(t1, t1 * p2);
      h2 pd = t0 * a0 + t1 * a1;
      part[e] = (float)pd[0] + (float)pd[1];
    }

    // prefetch next group's xl gathers before the reduce chain
#pragma unroll
    for (int e = 0; e < 4; e++) {
      int sx = ns[e] < 0 ? 0 : ns[e];
      nx[e] = *(const h4*)&xl[(size_t)sx * HC + c0];
    }

#pragma unroll
    for (int e = 0; e < 4; e++) part[e] += __shfl_xor(part[e], 1, 64);
#pragma unroll
    for (int e = 0; e < 4; e++) part[e] += __shfl_xor(part[e], 2, 64);
#pragma unroll
    for (int e = 0; e < 4; e++) part[e] += __shfl_xor(part[e], 4, 64);

#pragma unroll
    for (int e = 0; e < 4; e++) {
      float p = (cs[e] >= 0) ? __builtin_amdgcn_exp2f(part[e]) : 0.f;
      s += p;
#pragma unroll
      for (int i = 0; i < 4; i++) acc[i] += p * (float)cx[e][i];
    }

#pragma unroll
    for (int e = 0; e < 4; e++) { cs[e] = ns[e]; ce[e] = ne[e]; cx[e] = nx[e]; }
  }

  float inv = 1.f / (s + 1e-16f);
  h4 o;
#pragma unroll
  for (int i = 0; i < 4; i++) {
    float v = acc[i] * inv + bc[c0 + i];
    o[i] = (_Float16)(v > 0.f ? v : (__expf(v) - 1.f));   // elu
  }
  *(h4*)&out[(size_t)node * HC + c0] = o;
}

// ---------------------------------------------------------------- pooling + MLP

__global__ __launch_bounds__(256) void gbound_kernel(const int* __restrict__ batch,
                                                     int* __restrict__ gstart, int n) {
  int g = blockIdx.x * 256 + threadIdx.x;
  if (g > GNUM) return;
  int lo = 0, hi = n;
  while (lo < hi) {
    int mid = (lo + hi) >> 1;
    if (batch[mid] < g) lo = mid + 1; else hi = mid;
  }
  gstart[g] = lo;
}

__global__ __launch_bounds__(256) void pool2_kernel(const _Float16* __restrict__ h,
                                                    const int* __restrict__ gstart,
                                                    float* __restrict__ gmean) {
  __shared__ float red[256];
  int g = blockIdx.x;
  int t = threadIdx.x;
  int s = gstart[g], e = gstart[g + 1];
  int c = t & 31, rg = t >> 5;
  float acc = 0.f;
  for (int i = s + rg; i < e; i += 8) acc += (float)h[(size_t)i * 32 + c];
  red[t] = acc;
  __syncthreads();
  if (t < 128) red[t] += red[t + 128];
  __syncthreads();
  if (t < 64) red[t] += red[t + 64];
  __syncthreads();
  if (t < 32) {
    float v = red[t] + red[t + 32];
    gmean[g * 32 + t] = v / fmaxf((float)(e - s), 1.f);
  }
}

__global__ __launch_bounds__(64) void fc_kernel(const float* __restrict__ gmean,
                                                const float* __restrict__ w1,
                                                const float* __restrict__ b1,
                                                const float* __restrict__ w2,
                                                const float* __restrict__ b2,
                                                float* __restrict__ out) {
  __shared__ float g[32];
  __shared__ float a1[64];
  int gi = blockIdx.x;
  int t = threadIdx.x;
  if (t < 32) g[t] = gmean[gi * 32 + t];
  __syncthreads();
  float v = b1[t];
  for (int k = 0; k < 32; k++) v += g[k] * w1[k * 64 + t];
  a1[t] = v > 0.f ? v : (__expf(v) - 1.f);
  __syncthreads();
  if (t < 4) {
    float o = b2[t];
    for (int k = 0; k < 64; k++) o += a1[k] * w2[k * 4 + t];
    out[gi * 4 + t] = o;
  }
}

// ---------------------------------------------------------------- launch

extern "C" void kernel_launch(void* const* d_in, const int* in_sizes, int n_in,
                              void* d_out, int out_size, void* d_ws, size_t ws_size,
                              hipStream_t stream) {
  const float* x     = (const float*)d_in[0];
  const int*   ei    = (const int*)d_in[1];
  const float* eattr = (const float*)d_in[2];
  const int*   batch = (const int*)d_in[3];
  const float *wl1 = (const float*)d_in[4],  *bl1 = (const float*)d_in[5];
  const float *wr1 = (const float*)d_in[6],  *br1 = (const float*)d_in[7];
  const float *we1 = (const float*)d_in[8],  *at1 = (const float*)d_in[9];
  const float *bc1 = (const float*)d_in[10];
  const float *wl2 = (const float*)d_in[11], *bl2 = (const float*)d_in[12];
  const float *wr2 = (const float*)d_in[13], *br2 = (const float*)d_in[14];
  const float *we2 = (const float*)d_in[15], *at2 = (const float*)d_in[16];
  const float *bc2 = (const float*)d_in[17];
  const float *wl3 = (const float*)d_in[18], *bl3 = (const float*)d_in[19];
  const float *wr3 = (const float*)d_in[20], *br3 = (const float*)d_in[21];
  const float *we3 = (const float*)d_in[22], *at3 = (const float*)d_in[23];
  const float *bc3 = (const float*)d_in[24];
  const float *wf1 = (const float*)d_in[25], *bf1 = (const float*)d_in[26];
  const float *wf2 = (const float*)d_in[27], *bf2 = (const float*)d_in[28];

  int N = in_sizes[0] / 16;
  int E = in_sizes[1] / 2;
  const int* srcp = ei;
  const int* dstp = ei + E;
  int EApad = E + 4 * N;      // CSR upper bound incl. self-loops + padding
  int NB = (N + 511) / 512;   // scan blocks (<=1024)

  char* wsb = (char*)d_ws;
  size_t off = 0;
  auto alloc = [&](size_t bytes) -> char* {
    char* p = wsb + off;
    off += (bytes + 255) & ~(size_t)255;
    return p;
  };
  int*       cnt     = (int*)alloc((size_t)N * 4);
  int*       row_ptr = (int*)alloc((size_t)(N + 1) * 4);
  int*       fill    = (int*)alloc((size_t)N * 4);
  int*       bpart   = (int*)alloc((size_t)1024 * 4);
  int*       boff    = (int*)alloc((size_t)1024 * 4);
  int*       csr_src = (int*)alloc((size_t)EApad * 4);
  _Float16*  ea_csr  = (_Float16*)alloc((size_t)EApad * 8 * 2);
  _Float16*  xl      = (_Float16*)alloc((size_t)N * 128 * 2);
  _Float16*  xr      = (_Float16*)alloc((size_t)N * 128 * 2);
  _Float16*  h16     = (_Float16*)alloc((size_t)N * 128 * 2);
  _Float16*  h3      = (_Float16*)alloc((size_t)N * 32 * 2);
  _Float16*  x16     = (_Float16*)alloc((size_t)N * 16 * 2);
  float*     gmean   = (float*)alloc((size_t)GNUM * 32 * 4);
  int*       gstart  = (int*)alloc((size_t)(GNUM + 1) * 4);
  _Float16*  wp1l    = (_Float16*)alloc((size_t)32 * 128 * 2);
  _Float16*  wp1r    = (_Float16*)alloc((size_t)32 * 128 * 2);
  _Float16*  wp2l    = (_Float16*)alloc((size_t)128 * 128 * 2);
  _Float16*  wp2r    = (_Float16*)alloc((size_t)128 * 128 * 2);
  _Float16*  wp3l    = (_Float16*)alloc((size_t)128 * 32 * 2);
  _Float16*  wp3r    = (_Float16*)alloc((size_t)128 * 32 * 2);

  hipMemsetAsync(cnt, 0, (size_t)N * 4, stream);

  hist_kernel<<<(E + 255) / 256, 256, 0, stream>>>(dstp, cnt, E);
  scan_part_kernel<<<NB, 256, 0, stream>>>(cnt, bpart, N);
  scan_top_kernel<<<1, 1024, 0, stream>>>(bpart, boff, row_ptr, NB, N);
  scan_write_kernel<<<NB, 256, 0, stream>>>(cnt, boff, row_ptr, fill, N);
  scatter_kernel<<<(E + 255) / 256, 256, 0, stream>>>(srcp, dstp, eattr, fill, csr_src, ea_csr, E);
  selfloop_kernel<<<(N * 8 + 255) / 256, 256, 0, stream>>>(row_ptr, fill, csr_src, ea_csr, N);
  gbound_kernel<<<1, 256, 0, stream>>>(batch, gstart, N);
  cvt16_kernel<<<(N * 4 + 255) / 256, 256, 0, stream>>>(x, x16, N * 4);
  // pack MFMA weights: (NC/16)*(Kpad/32)*64 threads each
  pack_kernel<<<dim3(2, 2), 256, 0, stream>>>(wl1, wp1l, wr1, wp1r, 16, 32, 128);
  pack_kernel<<<dim3(8, 2), 256, 0, stream>>>(wl2, wp2l, wr2, wp2r, 128, 128, 128);
  pack_kernel<<<dim3(2, 2), 256, 0, stream>>>(wl3, wp3l, wr3, wp3r, 128, 128, 32);

  // layer 1: K=16 -> 128 (fp16 MFMA, K zero-padded to 32)
  k1m16_kernel<128><<<dim3((N + 63) / 64, 2), 256, 0, stream>>>(
      x16, wp1l, bl1, xl, wp1r, br1, xr, N);
  k2_kernel<4><<<(N + 3) / 4, 128, 0, stream>>>(xl, xr, row_ptr, csr_src, ea_csr,
                                                we1, at1, bc1, h16, N);
  // layer 2: K=128 -> 128 (fp16 MFMA)
  k1m_kernel<128, 128><<<dim3((N + 63) / 64, 2), 256, 0, stream>>>(
      h16, wp2l, bl2, xl, wp2r, br2, xr, N);
  k2_kernel<4><<<(N + 3) / 4, 128, 0, stream>>>(xl, xr, row_ptr, csr_src, ea_csr,
                                                we2, at2, bc2, h16, N);
  // layer 3: K=128 -> 32 (fp16 MFMA, single head)
  k1m_kernel<128, 32><<<dim3((N + 63) / 64, 2), 256, 0, stream>>>(
      h16, wp3l, bl3, xl, wp3r, br3, xr, N);
  k2_kernel<1><<<(N + 15) / 16, 128, 0, stream>>>(xl, xr, row_ptr, csr_src, ea_csr,
                                                  we3, at3, bc3, h3, N);

  pool2_kernel<<<GNUM, 256, 0, stream>>>(h3, gstart, gmean);
  fc_kernel<<<GNUM, 64, 0, stream>>>(gmean, wf1, bf1, wf2, bf2, (float*)d_out);
}

// Round 9
// 717.045 us; speedup vs baseline: 1.0499x; 1.0499x over previous
//
#include <hip/hip_runtime.h>
#include <cstdint>
#include <type_traits>

// GNN GATv2 x3 + mean-pool + MLP.
// All three node-transform GEMMs on fp16 MFMA (layer1 K=16 zero-padded to 32).
// fp16 feature tables + fp16 CSR-ordered edge features (self-loop = last CSR
// entry, unpadded — R8's pad-to-4 + 4-wide unroll blew VGPR 36->52 and dropped
// occupancy 65->39%: regression. k2 is R7's 2-wide pipeline at VGPR=36.)
constexpr int GNUM = 128;   // graphs

typedef _Float16 h2 __attribute__((ext_vector_type(2)));
typedef _Float16 h4 __attribute__((ext_vector_type(4)));
typedef _Float16 h8 __attribute__((ext_vector_type(8)));
typedef float f4 __attribute__((ext_vector_type(4)));

// ---------------------------------------------------------------- setup kernels

__global__ __launch_bounds__(256) void hist_kernel(const int* __restrict__ dst,
                                                   int* __restrict__ cnt, int E) {
  int i = blockIdx.x * 256 + threadIdx.x;
  if (i < E) atomicAdd(&cnt[dst[i]], 1);
}

// ---- 3-phase parallel exclusive scan of (cnt[i]+1), 512 elems per block ----
__global__ __launch_bounds__(256) void scan_part_kernel(const int* __restrict__ cnt,
                                                        int* __restrict__ bpart, int n) {
  __shared__ int red[256];
  int base = blockIdx.x * 512;
  int t = threadIdx.x;
  int s = 0;
  int i0 = base + t, i1 = base + 256 + t;
  if (i0 < n) s += cnt[i0] + 1;
  if (i1 < n) s += cnt[i1] + 1;
  red[t] = s;
  __syncthreads();
  for (int off = 128; off > 0; off >>= 1) {
    if (t < off) red[t] += red[t + off];
    __syncthreads();
  }
  if (t == 0) bpart[blockIdx.x] = red[0];
}

__global__ __launch_bounds__(1024) void scan_top_kernel(const int* __restrict__ bpart,
                                                        int* __restrict__ boff,
                                                        int* __restrict__ row_ptr,
                                                        int B, int n) {
  __shared__ int buf[1024];
  int t = threadIdx.x;
  buf[t] = (t < B) ? bpart[t] : 0;
  __syncthreads();
  for (int off = 1; off < 1024; off <<= 1) {
    int v = (t >= off) ? buf[t - off] : 0;
    __syncthreads();
    buf[t] += v;
    __syncthreads();
  }
  if (t < B) boff[t] = (t == 0) ? 0 : buf[t - 1];
  if (t == 0) row_ptr[n] = buf[1023];
}

__global__ __launch_bounds__(256) void scan_write_kernel(const int* __restrict__ cnt,
                                                         const int* __restrict__ boff,
                                                         int* __restrict__ row_ptr,
                                                         int* __restrict__ fill, int n) {
  __shared__ int red[256];
  int base = blockIdx.x * 512;
  int t = threadIdx.x;
  int i0 = base + 2 * t, i1 = base + 2 * t + 1;
  int v0 = (i0 < n) ? cnt[i0] + 1 : 0;
  int v1 = (i1 < n) ? cnt[i1] + 1 : 0;
  int val = v0 + v1;
  red[t] = val;
  __syncthreads();
  for (int off = 1; off < 256; off <<= 1) {
    int u = (t >= off) ? red[t - off] : 0;
    __syncthreads();
    red[t] += u;
    __syncthreads();
  }
  int o = boff[blockIdx.x] + red[t] - val;   // exclusive prefix for this pair
  if (i0 < n) { row_ptr[i0] = o; fill[i0] = o; }
  if (i1 < n) { row_ptr[i1] = o + v0; fill[i1] = o + v0; }
}

// scatter edges into CSR slots; write fp16 edge features directly in CSR order
__global__ __launch_bounds__(256) void scatter_kernel(const int* __restrict__ src,
                                                      const int* __restrict__ dst,
                                                      const float* __restrict__ ea,
                                                      int* __restrict__ fill,
                                                      int* __restrict__ csr_src,
                                                      _Float16* __restrict__ ea_csr, int E) {
  int i = blockIdx.x * 256 + threadIdx.x;
  if (i >= E) return;
  int d = dst[i];
  int p = atomicAdd(&fill[d], 1);
  csr_src[p] = src[i];
  float4 e0 = *(const float4*)&ea[(size_t)i * 8];
  float4 e1 = *(const float4*)&ea[(size_t)i * 8 + 4];
  h8 v;
  v[0] = (_Float16)e0.x; v[1] = (_Float16)e0.y; v[2] = (_Float16)e0.z; v[3] = (_Float16)e0.w;
  v[4] = (_Float16)e1.x; v[5] = (_Float16)e1.y; v[6] = (_Float16)e1.z; v[7] = (_Float16)e1.w;
  *(h8*)&ea_csr[(size_t)p * 8] = v;
}

// fill self-loop slot (last of each segment) with segment-mean attrs.
// 8 threads per node (one per edge channel).
__global__ __launch_bounds__(256) void selfloop_kernel(const int* __restrict__ row_ptr,
                                                       int* __restrict__ csr_src,
                                                       _Float16* __restrict__ ea_csr, int n) {
  int idx = blockIdx.x * 256 + threadIdx.x;
  int i = idx >> 3, c = idx & 7;
  if (i >= n) return;
  int s = row_ptr[i], e = row_ptr[i + 1] - 1;   // [s,e) real edges, e = self slot
  float a = 0.f;
  for (int j = s; j < e; j++) a += (float)ea_csr[(size_t)j * 8 + c];
  float inv = 1.f / fmaxf((float)(e - s), 1.f);
  ea_csr[(size_t)e * 8 + c] = (_Float16)(a * inv);
  if (c == 0) csr_src[e] = i;
}

// pack w [Kreal][NC] f32 -> fp16 MFMA B-fragment order with zero-padding to Kpad
__global__ __launch_bounds__(256) void pack_kernel(const float* __restrict__ w0,
                                                   _Float16* __restrict__ wp0,
                                                   const float* __restrict__ w1,
                                                   _Float16* __restrict__ wp1,
                                                   int Kreal, int Kpad, int NC) {
  const float* w = blockIdx.y ? w1 : w0;
  _Float16* wp = blockIdx.y ? wp1 : wp0;
  int KB = Kpad / 32;
  int total = (NC / 16) * KB * 64;
  int idx = blockIdx.x * 256 + threadIdx.x;
  if (idx >= total) return;
  int lane = idx & 63;
  int blk = idx >> 6;
  int nt = blk / KB, kb = blk % KB;
  int col = nt * 16 + (lane & 15);
  int krow = kb * 32 + (lane >> 4) * 8;
  h8 v;
#pragma unroll
  for (int j = 0; j < 8; j++)
    v[j] = (krow + j < Kreal) ? (_Float16)w[(size_t)(krow + j) * NC + col] : (_Float16)0.f;
  *(h8*)&wp[(size_t)idx * 8] = v;
}

// f32 -> fp16 convert (vectorized by 4)
__global__ __launch_bounds__(256) void cvt16_kernel(const float* __restrict__ x,
                                                    _Float16* __restrict__ x16, int total4) {
  int i = blockIdx.x * 256 + threadIdx.x;
  if (i >= total4) return;
  float4 v = ((const float4*)x)[i];
  h4 o;
  o[0] = (_Float16)v.x; o[1] = (_Float16)v.y; o[2] = (_Float16)v.z; o[3] = (_Float16)v.w;
  ((h4*)x16)[i] = o;
}

// ---------------------------------------------------------------- node transform GEMMs

// fp16 MFMA, K=128. 256 thr = 4 waves, 16 nodes/wave, 64 nodes/block.
template <int K, int NCOLS>
__global__ __launch_bounds__(256) void k1m_kernel(const _Float16* __restrict__ x,
                                                  const _Float16* __restrict__ wp0,
                                                  const float* __restrict__ b0,
                                                  _Float16* __restrict__ out0,
                                                  const _Float16* __restrict__ wp1,
                                                  const float* __restrict__ b1,
                                                  _Float16* __restrict__ out1, int n) {
  constexpr int NT = NCOLS / 16, KB = K / 32;
  const _Float16* wp = blockIdx.y ? wp1 : wp0;
  const float* b = blockIdx.y ? b1 : b0;
  _Float16* out = blockIdx.y ? out1 : out0;

  int tid = threadIdx.x;
  int wave = tid >> 6, lane = tid & 63;
  int m = lane & 15, quad = lane >> 4;
  int node0 = blockIdx.x * 64 + wave * 16;

  h8 afrag[KB];
  int anode = node0 + m;
  if (anode < n) {
#pragma unroll
    for (int kb = 0; kb < KB; kb++)
      afrag[kb] = *(const h8*)&x[(size_t)anode * K + kb * 32 + quad * 8];
  } else {
#pragma unroll
    for (int kb = 0; kb < KB; kb++) afrag[kb] = (h8)(_Float16)0.f;
  }

  f4 acc[NT] = {};
#pragma unroll
  for (int nt = 0; nt < NT; nt++) {
#pragma unroll
    for (int kb = 0; kb < KB; kb++) {
      h8 bfrag = *(const h8*)&wp[((size_t)(nt * KB + kb) * 64 + lane) * 8];
      acc[nt] = __builtin_amdgcn_mfma_f32_16x16x32_f16(afrag[kb], bfrag, acc[nt], 0, 0, 0);
    }
  }

#pragma unroll
  for (int nt = 0; nt < NT; nt++) {
#pragma unroll
    for (int r = 0; r < 4; r++) {
      int row = node0 + quad * 4 + r;
      if (row < n) {
        int col = nt * 16 + m;
        out[(size_t)row * NCOLS + col] = (_Float16)(acc[nt][r] + b[col]);
      }
    }
  }
}

// fp16 MFMA, Kreal=16 zero-padded to 32 (layer 1). x16 rows of 16 halves.
template <int NCOLS>
__global__ __launch_bounds__(256) void k1m16_kernel(const _Float16* __restrict__ x16,
                                                    const _Float16* __restrict__ wp0,
                                                    const float* __restrict__ b0,
                                                    _Float16* __restrict__ out0,
                                                    const _Float16* __restrict__ wp1,
                                                    const float* __restrict__ b1,
                                                    _Float16* __restrict__ out1, int n) {
  constexpr int NT = NCOLS / 16;
  const _Float16* wp = blockIdx.y ? wp1 : wp0;
  const float* b = blockIdx.y ? b1 : b0;
  _Float16* out = blockIdx.y ? out1 : out0;

  int tid = threadIdx.x;
  int wave = tid >> 6, lane = tid & 63;
  int m = lane & 15, quad = lane >> 4;
  int node0 = blockIdx.x * 64 + wave * 16;

  int anode = node0 + m;
  h8 afrag;
  if (anode < n && quad < 2)
    afrag = *(const h8*)&x16[(size_t)anode * 16 + quad * 8];
  else
    afrag = (h8)(_Float16)0.f;

  f4 acc[NT] = {};
#pragma unroll
  for (int nt = 0; nt < NT; nt++) {
    h8 bfrag = *(const h8*)&wp[((size_t)nt * 64 + lane) * 8];
    acc[nt] = __builtin_amdgcn_mfma_f32_16x16x32_f16(afrag, bfrag, acc[nt], 0, 0, 0);
  }

#pragma unroll
  for (int nt = 0; nt < NT; nt++) {
#pragma unroll
    for (int r = 0; r < 4; r++) {
      int row = node0 + quad * 4 + r;
      if (row < n) {
        int col = nt * 16 + m;
        out[(size_t)row * NCOLS + col] = (_Float16)(acc[nt][r] + b[col]);
      }
    }
  }
}

// ---------------------------------------------------------------- fused GATv2 edge+softmax+aggregate
// One-pass softmax (no max-shift; logits O(1)). Self-loop is a normal CSR entry
// (so every segment has len >= 1). Packed-fp16 logit math; att pre-scaled by
// log2(e). 2-edge software pipeline (R7 champion: VGPR=36, occ 65%).
template <int H>
__global__ __launch_bounds__(128) void k2_kernel(
    const _Float16* __restrict__ xl, const _Float16* __restrict__ xr,
    const int* __restrict__ row_ptr, const int* __restrict__ csr_src,
    const _Float16* __restrict__ ea_csr, const float* __restrict__ we,
    const float* __restrict__ att, const float* __restrict__ bc,
    _Float16* __restrict__ out, int n) {
  constexpr int HC = H * 32;
  constexpr int NL = HC / 4;   // lanes per node (32 or 8)
  constexpr int NPB = 128 / NL;

  int tid = threadIdx.x;
  int ln = tid / NL, q = tid % NL;
  int c0 = 4 * q;
  int node = blockIdx.x * NPB + ln;
  if (node >= n) return;

  h2 w2[8][2];
#pragma unroll
  for (int k = 0; k < 8; k++) {
    float4 v = *(const float4*)&we[k * HC + c0];
    w2[k][0] = h2{(_Float16)v.x, (_Float16)v.y};
    w2[k][1] = h2{(_Float16)v.z, (_Float16)v.w};
  }
  const float LOG2E = 1.44269504088896f;
  float4 av = *(const float4*)&att[c0];
  h2 a0 = h2{(_Float16)(av.x * LOG2E), (_Float16)(av.y * LOG2E)};
  h2 a1 = h2{(_Float16)(av.z * LOG2E), (_Float16)(av.w * LOG2E)};
  h4 xrh = *(const h4*)&xr[(size_t)node * HC + c0];
  h2 xr0 = h2{xrh[0], xrh[1]}, xr1 = h2{xrh[2], xrh[3]};
  const h2 p2 = h2{(_Float16)0.2f, (_Float16)0.2f};

  float acc[4] = {0.f, 0.f, 0.f, 0.f};
  float s = 0.f;

  int start = row_ptr[node], end = row_ptr[node + 1];   // len >= 1 (self loop)
  int len = end - start;
  int pairs = (len + 1) >> 1;

  // prologue: load pair 0 (clamped)
  int j1 = (start + 1 < end) ? start + 1 : start;
  float m1 = (start + 1 < end) ? 1.f : 0.f;
  int s0 = csr_src[start], s1 = csr_src[j1];
  h8 e0 = *(const h8*)&ea_csr[(size_t)start * 8];
  h8 e1 = *(const h8*)&ea_csr[(size_t)j1 * 8];
  h4 x0 = *(const h4*)&xl[(size_t)s0 * HC + c0];
  h4 x1 = *(const h4*)&xl[(size_t)s1 * HC + c0];

  for (int p = 0; p < pairs; p++) {
    // ---- issue next pair's src/ea loads (clamped; unused garbage on last) ----
    int jn = start + 2 * (p + 1);
    int k0 = (jn < end) ? jn : start;
    int k1 = (jn + 1 < end) ? jn + 1 : k0;
    float nm1 = (jn + 1 < end) ? 1.f : 0.f;
    int ns0 = csr_src[k0], ns1 = csr_src[k1];
    h8 ne0 = *(const h8*)&ea_csr[(size_t)k0 * 8];
    h8 ne1 = *(const h8*)&ea_csr[(size_t)k1 * 8];

    // ---- logits for current pair (two independent chains) ----
    h2 t00 = h2{x0[0], x0[1]} + xr0;
    h2 t01 = h2{x0[2], x0[3]} + xr1;
    h2 t10 = h2{x1[0], x1[1]} + xr0;
    h2 t11 = h2{x1[2], x1[3]} + xr1;
#pragma unroll
    for (int k = 0; k < 8; k++) {
      h2 ev0 = h2{e0[k], e0[k]};
      h2 ev1 = h2{e1[k], e1[k]};
      t00 += ev0 * w2[k][0];
      t01 += ev0 * w2[k][1];
      t10 += ev1 * w2[k][0];
      t11 += ev1 * w2[k][1];
    }
    t00 = __builtin_elementwise_max(t00, t00 * p2);
    t01 = __builtin_elementwise_max(t01, t01 * p2);
    t10 = __builtin_elementwise_max(t10, t10 * p2);
    t11 = __builtin_elementwise_max(t11, t11 * p2);
    h2 pd0 = t00 * a0 + t01 * a1;
    h2 pd1 = t10 * a0 + t11 * a1;
    float part0 = (float)pd0[0] + (float)pd0[1];
    float part1 = (float)pd1[0] + (float)pd1[1];

    // ---- issue next pair's xl gathers before the reduce chain ----
    h4 nx0 = *(const h4*)&xl[(size_t)ns0 * HC + c0];
    h4 nx1 = *(const h4*)&xl[(size_t)ns1 * HC + c0];

    // ---- reduce across the 8 lanes of each head, exp, accumulate ----
    part0 += __shfl_xor(part0, 1, 64);
    part1 += __shfl_xor(part1, 1, 64);
    part0 += __shfl_xor(part0, 2, 64);
    part1 += __shfl_xor(part1, 2, 64);
    part0 += __shfl_xor(part0, 4, 64);
    part1 += __shfl_xor(part1, 4, 64);
    float pe0 = __builtin_amdgcn_exp2f(part0);
    float pe1 = __builtin_amdgcn_exp2f(part1) * m1;
    s += pe0 + pe1;
#pragma unroll
    for (int i = 0; i < 4; i++)
      acc[i] += pe0 * (float)x0[i] + pe1 * (float)x1[i];

    // ---- rotate pipeline registers ----
    s0 = ns0; s1 = ns1; e0 = ne0; e1 = ne1; x0 = nx0; x1 = nx1; m1 = nm1;
  }

  float inv = 1.f / (s + 1e-16f);
  h4 o;
#pragma unroll
  for (int i = 0; i < 4; i++) {
    float v = acc[i] * inv + bc[c0 + i];
    o[i] = (_Float16)(v > 0.f ? v : (__expf(v) - 1.f));   // elu
  }
  *(h4*)&out[(size_t)node * HC + c0] = o;
}

// ---------------------------------------------------------------- pooling + MLP

__global__ __launch_bounds__(256) void gbound_kernel(const int* __restrict__ batch,
                                                     int* __restrict__ gstart, int n) {
  int g = blockIdx.x * 256 + threadIdx.x;
  if (g > GNUM) return;
  int lo = 0, hi = n;
  while (lo < hi) {
    int mid = (lo + hi) >> 1;
    if (batch[mid] < g) lo = mid + 1; else hi = mid;
  }
  gstart[g] = lo;
}

__global__ __launch_bounds__(256) void pool2_kernel(const _Float16* __restrict__ h,
                                                    const int* __restrict__ gstart,
                                                    float* __restrict__ gmean) {
  __shared__ float red[256];
  int g = blockIdx.x;
  int t = threadIdx.x;
  int s = gstart[g], e = gstart[g + 1];
  int c = t & 31, rg = t >> 5;
  float acc = 0.f;
  for (int i = s + rg; i < e; i += 8) acc += (float)h[(size_t)i * 32 + c];
  red[t] = acc;
  __syncthreads();
  if (t < 128) red[t] += red[t + 128];
  __syncthreads();
  if (t < 64) red[t] += red[t + 64];
  __syncthreads();
  if (t < 32) {
    float v = red[t] + red[t + 32];
    gmean[g * 32 + t] = v / fmaxf((float)(e - s), 1.f);
  }
}

__global__ __launch_bounds__(64) void fc_kernel(const float* __restrict__ gmean,
                                                const float* __restrict__ w1,
                                                const float* __restrict__ b1,
                                                const float* __restrict__ w2,
                                                const float* __restrict__ b2,
                                                float* __restrict__ out) {
  __shared__ float g[32];
  __shared__ float a1[64];
  int gi = blockIdx.x;
  int t = threadIdx.x;
  if (t < 32) g[t] = gmean[gi * 32 + t];
  __syncthreads();
  float v = b1[t];
  for (int k = 0; k < 32; k++) v += g[k] * w1[k * 64 + t];
  a1[t] = v > 0.f ? v : (__expf(v) - 1.f);
  __syncthreads();
  if (t < 4) {
    float o = b2[t];
    for (int k = 0; k < 64; k++) o += a1[k] * w2[k * 4 + t];
    out[gi * 4 + t] = o;
  }
}

// ---------------------------------------------------------------- launch

extern "C" void kernel_launch(void* const* d_in, const int* in_sizes, int n_in,
                              void* d_out, int out_size, void* d_ws, size_t ws_size,
                              hipStream_t stream) {
  const float* x     = (const float*)d_in[0];
  const int*   ei    = (const int*)d_in[1];
  const float* eattr = (const float*)d_in[2];
  const int*   batch = (const int*)d_in[3];
  const float *wl1 = (const float*)d_in[4],  *bl1 = (const float*)d_in[5];
  const float *wr1 = (const float*)d_in[6],  *br1 = (const float*)d_in[7];
  const float *we1 = (const float*)d_in[8],  *at1 = (const float*)d_in[9];
  const float *bc1 = (const float*)d_in[10];
  const float *wl2 = (const float*)d_in[11], *bl2 = (const float*)d_in[12];
  const float *wr2 = (const float*)d_in[13], *br2 = (const float*)d_in[14];
  const float *we2 = (const float*)d_in[15], *at2 = (const float*)d_in[16];
  const float *bc2 = (const float*)d_in[17];
  const float *wl3 = (const float*)d_in[18], *bl3 = (const float*)d_in[19];
  const float *wr3 = (const float*)d_in[20], *br3 = (const float*)d_in[21];
  const float *we3 = (const float*)d_in[22], *at3 = (const float*)d_in[23];
  const float *bc3 = (const float*)d_in[24];
  const float *wf1 = (const float*)d_in[25], *bf1 = (const float*)d_in[26];
  const float *wf2 = (const float*)d_in[27], *bf2 = (const float*)d_in[28];

  int N = in_sizes[0] / 16;
  int E = in_sizes[1] / 2;
  const int* srcp = ei;
  const int* dstp = ei + E;
  int EA = E + N;             // CSR entries incl. self-loops
  int NB = (N + 511) / 512;   // scan blocks (<=1024)

  char* wsb = (char*)d_ws;
  size_t off = 0;
  auto alloc = [&](size_t bytes) -> char* {
    char* p = wsb + off;
    off += (bytes + 255) & ~(size_t)255;
    return p;
  };
  int*       cnt     = (int*)alloc((size_t)N * 4);
  int*       row_ptr = (int*)alloc((size_t)(N + 1) * 4);
  int*       fill    = (int*)alloc((size_t)N * 4);
  int*       bpart   = (int*)alloc((size_t)1024 * 4);
  int*       boff    = (int*)alloc((size_t)1024 * 4);
  int*       csr_src = (int*)alloc((size_t)EA * 4);
  _Float16*  ea_csr  = (_Float16*)alloc((size_t)EA * 8 * 2);
  _Float16*  xl      = (_Float16*)alloc((size_t)N * 128 * 2);
  _Float16*  xr      = (_Float16*)alloc((size_t)N * 128 * 2);
  _Float16*  h16     = (_Float16*)alloc((size_t)N * 128 * 2);
  _Float16*  h3      = (_Float16*)alloc((size_t)N * 32 * 2);
  _Float16*  x16     = (_Float16*)alloc((size_t)N * 16 * 2);
  float*     gmean   = (float*)alloc((size_t)GNUM * 32 * 4);
  int*       gstart  = (int*)alloc((size_t)(GNUM + 1) * 4);
  _Float16*  wp1l    = (_Float16*)alloc((size_t)32 * 128 * 2);
  _Float16*  wp1r    = (_Float16*)alloc((size_t)32 * 128 * 2);
  _Float16*  wp2l    = (_Float16*)alloc((size_t)128 * 128 * 2);
  _Float16*  wp2r    = (_Float16*)alloc((size_t)128 * 128 * 2);
  _Float16*  wp3l    = (_Float16*)alloc((size_t)128 * 32 * 2);
  _Float16*  wp3r    = (_Float16*)alloc((size_t)128 * 32 * 2);

  hipMemsetAsync(cnt, 0, (size_t)N * 4, stream);

  hist_kernel<<<(E + 255) / 256, 256, 0, stream>>>(dstp, cnt, E);
  scan_part_kernel<<<NB, 256, 0, stream>>>(cnt, bpart, N);
  scan_top_kernel<<<1, 1024, 0, stream>>>(bpart, boff, row_ptr, NB, N);
  scan_write_kernel<<<NB, 256, 0, stream>>>(cnt, boff, row_ptr, fill, N);
  scatter_kernel<<<(E + 255) / 256, 256, 0, stream>>>(srcp, dstp, eattr, fill, csr_src, ea_csr, E);
  selfloop_kernel<<<(N * 8 + 255) / 256, 256, 0, stream>>>(row_ptr, csr_src, ea_csr, N);
  gbound_kernel<<<1, 256, 0, stream>>>(batch, gstart, N);
  cvt16_kernel<<<(N * 4 + 255) / 256, 256, 0, stream>>>(x, x16, N * 4);
  // pack MFMA weights: (NC/16)*(Kpad/32)*64 threads each
  pack_kernel<<<dim3(2, 2), 256, 0, stream>>>(wl1, wp1l, wr1, wp1r, 16, 32, 128);
  pack_kernel<<<dim3(8, 2), 256, 0, stream>>>(wl2, wp2l, wr2, wp2r, 128, 128, 128);
  pack_kernel<<<dim3(2, 2), 256, 0, stream>>>(wl3, wp3l, wr3, wp3r, 128, 128, 32);

  // layer 1: K=16 -> 128 (fp16 MFMA, K zero-padded to 32)
  k1m16_kernel<128><<<dim3((N + 63) / 64, 2), 256, 0, stream>>>(
      x16, wp1l, bl1, xl, wp1r, br1, xr, N);
  k2_kernel<4><<<(N + 3) / 4, 128, 0, stream>>>(xl, xr, row_ptr, csr_src, ea_csr,
                                                we1, at1, bc1, h16, N);
  // layer 2: K=128 -> 128 (fp16 MFMA)
  k1m_kernel<128, 128><<<dim3((N + 63) / 64, 2), 256, 0, stream>>>(
      h16, wp2l, bl2, xl, wp2r, br2, xr, N);
  k2_kernel<4><<<(N + 3) / 4, 128, 0, stream>>>(xl, xr, row_ptr, csr_src, ea_csr,
                                                we2, at2, bc2, h16, N);
  // layer 3: K=128 -> 32 (fp16 MFMA, single head)
  k1m_kernel<128, 32><<<dim3((N + 63) / 64, 2), 256, 0, stream>>>(
      h16, wp3l, bl3, xl, wp3r, br3, xr, N);
  k2_kernel<1><<<(N + 15) / 16, 128, 0, stream>>>(xl, xr, row_ptr, csr_src, ea_csr,
                                                  we3, at3, bc3, h3, N);

  pool2_kernel<<<GNUM, 256, 0, stream>>>(h3, gstart, gmean);
  fc_kernel<<<GNUM, 64, 0, stream>>>(gmean, wf1, bf1, wf2, bf2, (float*)d_out);
}

// Round 10
// 684.599 us; speedup vs baseline: 1.0997x; 1.0474x over previous
//
#include <hip/hip_runtime.h>
#include <cstdint>
#include <type_traits>

// GNN GATv2 x3 + mean-pool + MLP.
// All GEMMs on fp16 MFMA; fp16 tables; fp16 CSR edge features (self-loop =
// last CSR entry). k2 = R7 2-wide pipeline (VGPR36) + unroll-2 to kill the
// rotation movs. R10: dispatch consolidation 20->15 (gbound->scan_top,
// pack x3 -> pack_all, cvt16 folded into k1m16, pool2+fc -> poolfc).
constexpr int GNUM = 128;   // graphs

typedef _Float16 h2 __attribute__((ext_vector_type(2)));
typedef _Float16 h4 __attribute__((ext_vector_type(4)));
typedef _Float16 h8 __attribute__((ext_vector_type(8)));
typedef float f4 __attribute__((ext_vector_type(4)));

// ---------------------------------------------------------------- setup kernels

__global__ __launch_bounds__(256) void hist_kernel(const int* __restrict__ dst,
                                                   int* __restrict__ cnt, int E) {
  int i = blockIdx.x * 256 + threadIdx.x;
  if (i < E) atomicAdd(&cnt[dst[i]], 1);
}

// ---- 3-phase parallel exclusive scan of (cnt[i]+1), 512 elems per block ----
__global__ __launch_bounds__(256) void scan_part_kernel(const int* __restrict__ cnt,
                                                        int* __restrict__ bpart, int n) {
  __shared__ int red[256];
  int base = blockIdx.x * 512;
  int t = threadIdx.x;
  int s = 0;
  int i0 = base + t, i1 = base + 256 + t;
  if (i0 < n) s += cnt[i0] + 1;
  if (i1 < n) s += cnt[i1] + 1;
  red[t] = s;
  __syncthreads();
  for (int off = 128; off > 0; off >>= 1) {
    if (t < off) red[t] += red[t + off];
    __syncthreads();
  }
  if (t == 0) bpart[blockIdx.x] = red[0];
}

// scan of block partials + (fused) graph-boundary binary search
__global__ __launch_bounds__(1024) void scan_top_kernel(const int* __restrict__ bpart,
                                                        int* __restrict__ boff,
                                                        int* __restrict__ row_ptr,
                                                        const int* __restrict__ batch,
                                                        int* __restrict__ gstart,
                                                        int B, int n) {
  __shared__ int buf[1024];
  int t = threadIdx.x;
  buf[t] = (t < B) ? bpart[t] : 0;
  __syncthreads();
  for (int off = 1; off < 1024; off <<= 1) {
    int v = (t >= off) ? buf[t - off] : 0;
    __syncthreads();
    buf[t] += v;
    __syncthreads();
  }
  if (t < B) boff[t] = (t == 0) ? 0 : buf[t - 1];
  if (t == 0) row_ptr[n] = buf[1023];
  // fused gbound: graph g's node range start (batch is sorted)
  if (t <= GNUM) {
    int lo = 0, hi = n;
    while (lo < hi) {
      int mid = (lo + hi) >> 1;
      if (batch[mid] < t) lo = mid + 1; else hi = mid;
    }
    gstart[t] = lo;
  }
}

__global__ __launch_bounds__(256) void scan_write_kernel(const int* __restrict__ cnt,
                                                         const int* __restrict__ boff,
                                                         int* __restrict__ row_ptr,
                                                         int* __restrict__ fill, int n) {
  __shared__ int red[256];
  int base = blockIdx.x * 512;
  int t = threadIdx.x;
  int i0 = base + 2 * t, i1 = base + 2 * t + 1;
  int v0 = (i0 < n) ? cnt[i0] + 1 : 0;
  int v1 = (i1 < n) ? cnt[i1] + 1 : 0;
  int val = v0 + v1;
  red[t] = val;
  __syncthreads();
  for (int off = 1; off < 256; off <<= 1) {
    int u = (t >= off) ? red[t - off] : 0;
    __syncthreads();
    red[t] += u;
    __syncthreads();
  }
  int o = boff[blockIdx.x] + red[t] - val;   // exclusive prefix for this pair
  if (i0 < n) { row_ptr[i0] = o; fill[i0] = o; }
  if (i1 < n) { row_ptr[i1] = o + v0; fill[i1] = o + v0; }
}

// scatter edges into CSR slots; write fp16 edge features directly in CSR order
__global__ __launch_bounds__(256) void scatter_kernel(const int* __restrict__ src,
                                                      const int* __restrict__ dst,
                                                      const float* __restrict__ ea,
                                                      int* __restrict__ fill,
                                                      int* __restrict__ csr_src,
                                                      _Float16* __restrict__ ea_csr, int E) {
  int i = blockIdx.x * 256 + threadIdx.x;
  if (i >= E) return;
  int d = dst[i];
  int p = atomicAdd(&fill[d], 1);
  csr_src[p] = src[i];
  float4 e0 = *(const float4*)&ea[(size_t)i * 8];
  float4 e1 = *(const float4*)&ea[(size_t)i * 8 + 4];
  h8 v;
  v[0] = (_Float16)e0.x; v[1] = (_Float16)e0.y; v[2] = (_Float16)e0.z; v[3] = (_Float16)e0.w;
  v[4] = (_Float16)e1.x; v[5] = (_Float16)e1.y; v[6] = (_Float16)e1.z; v[7] = (_Float16)e1.w;
  *(h8*)&ea_csr[(size_t)p * 8] = v;
}

// fill self-loop slot (last of each segment) with segment-mean attrs.
// 8 threads per node (one per edge channel).
__global__ __launch_bounds__(256) void selfloop_kernel(const int* __restrict__ row_ptr,
                                                       int* __restrict__ csr_src,
                                                       _Float16* __restrict__ ea_csr, int n) {
  int idx = blockIdx.x * 256 + threadIdx.x;
  int i = idx >> 3, c = idx & 7;
  if (i >= n) return;
  int s = row_ptr[i], e = row_ptr[i + 1] - 1;   // [s,e) real edges, e = self slot
  float a = 0.f;
  for (int j = s; j < e; j++) a += (float)ea_csr[(size_t)j * 8 + c];
  float inv = 1.f / fmaxf((float)(e - s), 1.f);
  ea_csr[(size_t)e * 8 + c] = (_Float16)(a * inv);
  if (c == 0) csr_src[e] = i;
}

// pack all 6 weight matrices f32 -> fp16 MFMA B-fragment order in one launch.
// blockIdx.y selects matrix; zero-pad K to Kpad.
__global__ __launch_bounds__(256) void pack_all_kernel(
    const float* __restrict__ wl1, _Float16* __restrict__ p1l,
    const float* __restrict__ wr1, _Float16* __restrict__ p1r,
    const float* __restrict__ wl2, _Float16* __restrict__ p2l,
    const float* __restrict__ wr2, _Float16* __restrict__ p2r,
    const float* __restrict__ wl3, _Float16* __restrict__ p3l,
    const float* __restrict__ wr3, _Float16* __restrict__ p3r) {
  int y = blockIdx.y;
  const float* w; _Float16* wp; int Kreal, Kpad, NC;
  switch (y) {
    case 0: w = wl1; wp = p1l; Kreal = 16;  Kpad = 32;  NC = 128; break;
    case 1: w = wr1; wp = p1r; Kreal = 16;  Kpad = 32;  NC = 128; break;
    case 2: w = wl2; wp = p2l; Kreal = 128; Kpad = 128; NC = 128; break;
    case 3: w = wr2; wp = p2r; Kreal = 128; Kpad = 128; NC = 128; break;
    case 4: w = wl3; wp = p3l; Kreal = 128; Kpad = 128; NC = 32;  break;
    default: w = wr3; wp = p3r; Kreal = 128; Kpad = 128; NC = 32; break;
  }
  int KB = Kpad / 32;
  int total = (NC / 16) * KB * 64;
  int idx = blockIdx.x * 256 + threadIdx.x;
  if (idx >= total) return;
  int lane = idx & 63;
  int blk = idx >> 6;
  int nt = blk / KB, kb = blk % KB;
  int col = nt * 16 + (lane & 15);
  int krow = kb * 32 + (lane >> 4) * 8;
  h8 v;
#pragma unroll
  for (int j = 0; j < 8; j++)
    v[j] = (krow + j < Kreal) ? (_Float16)w[(size_t)(krow + j) * NC + col] : (_Float16)0.f;
  *(h8*)&wp[(size_t)idx * 8] = v;
}

// ---------------------------------------------------------------- node transform GEMMs

// fp16 MFMA, K=128. 256 thr = 4 waves, 16 nodes/wave, 64 nodes/block.
template <int K, int NCOLS>
__global__ __launch_bounds__(256) void k1m_kernel(const _Float16* __restrict__ x,
                                                  const _Float16* __restrict__ wp0,
                                                  const float* __restrict__ b0,
                                                  _Float16* __restrict__ out0,
                                                  const _Float16* __restrict__ wp1,
                                                  const float* __restrict__ b1,
                                                  _Float16* __restrict__ out1, int n) {
  constexpr int NT = NCOLS / 16, KB = K / 32;
  const _Float16* wp = blockIdx.y ? wp1 : wp0;
  const float* b = blockIdx.y ? b1 : b0;
  _Float16* out = blockIdx.y ? out1 : out0;

  int tid = threadIdx.x;
  int wave = tid >> 6, lane = tid & 63;
  int m = lane & 15, quad = lane >> 4;
  int node0 = blockIdx.x * 64 + wave * 16;

  h8 afrag[KB];
  int anode = node0 + m;
  if (anode < n) {
#pragma unroll
    for (int kb = 0; kb < KB; kb++)
      afrag[kb] = *(const h8*)&x[(size_t)anode * K + kb * 32 + quad * 8];
  } else {
#pragma unroll
    for (int kb = 0; kb < KB; kb++) afrag[kb] = (h8)(_Float16)0.f;
  }

  f4 acc[NT] = {};
#pragma unroll
  for (int nt = 0; nt < NT; nt++) {
#pragma unroll
    for (int kb = 0; kb < KB; kb++) {
      h8 bfrag = *(const h8*)&wp[((size_t)(nt * KB + kb) * 64 + lane) * 8];
      acc[nt] = __builtin_amdgcn_mfma_f32_16x16x32_f16(afrag[kb], bfrag, acc[nt], 0, 0, 0);
    }
  }

#pragma unroll
  for (int nt = 0; nt < NT; nt++) {
#pragma unroll
    for (int r = 0; r < 4; r++) {
      int row = node0 + quad * 4 + r;
      if (row < n) {
        int col = nt * 16 + m;
        out[(size_t)row * NCOLS + col] = (_Float16)(acc[nt][r] + b[col]);
      }
    }
  }
}

// fp16 MFMA, Kreal=16 zero-padded to 32 (layer 1); reads f32 x directly and
// converts in-register (cvt16 pass folded in — R10).
template <int NCOLS>
__global__ __launch_bounds__(256) void k1m16_kernel(const float* __restrict__ x,
                                                    const _Float16* __restrict__ wp0,
                                                    const float* __restrict__ b0,
                                                    _Float16* __restrict__ out0,
                                                    const _Float16* __restrict__ wp1,
                                                    const float* __restrict__ b1,
                                                    _Float16* __restrict__ out1, int n) {
  constexpr int NT = NCOLS / 16;
  const _Float16* wp = blockIdx.y ? wp1 : wp0;
  const float* b = blockIdx.y ? b1 : b0;
  _Float16* out = blockIdx.y ? out1 : out0;

  int tid = threadIdx.x;
  int wave = tid >> 6, lane = tid & 63;
  int m = lane & 15, quad = lane >> 4;
  int node0 = blockIdx.x * 64 + wave * 16;

  int anode = node0 + m;
  h8 afrag = (h8)(_Float16)0.f;
  if (anode < n && quad < 2) {
    float4 v0 = *(const float4*)&x[(size_t)anode * 16 + quad * 8];
    float4 v1 = *(const float4*)&x[(size_t)anode * 16 + quad * 8 + 4];
    afrag[0] = (_Float16)v0.x; afrag[1] = (_Float16)v0.y;
    afrag[2] = (_Float16)v0.z; afrag[3] = (_Float16)v0.w;
    afrag[4] = (_Float16)v1.x; afrag[5] = (_Float16)v1.y;
    afrag[6] = (_Float16)v1.z; afrag[7] = (_Float16)v1.w;
  }

  f4 acc[NT] = {};
#pragma unroll
  for (int nt = 0; nt < NT; nt++) {
    h8 bfrag = *(const h8*)&wp[((size_t)nt * 64 + lane) * 8];
    acc[nt] = __builtin_amdgcn_mfma_f32_16x16x32_f16(afrag, bfrag, acc[nt], 0, 0, 0);
  }

#pragma unroll
  for (int nt = 0; nt < NT; nt++) {
#pragma unroll
    for (int r = 0; r < 4; r++) {
      int row = node0 + quad * 4 + r;
      if (row < n) {
        int col = nt * 16 + m;
        out[(size_t)row * NCOLS + col] = (_Float16)(acc[nt][r] + b[col]);
      }
    }
  }
}

// ---------------------------------------------------------------- fused GATv2 edge+softmax+aggregate
// One-pass softmax (no max-shift; logits O(1)). Self-loop is a normal CSR entry.
// Packed-fp16 logit math; att pre-scaled by log2(e). 2-edge software pipeline
// (R7 champion) + unroll-2 so the register rotation becomes renaming.
template <int H>
__global__ __launch_bounds__(128) void k2_kernel(
    const _Float16* __restrict__ xl, const _Float16* __restrict__ xr,
    const int* __restrict__ row_ptr, const int* __restrict__ csr_src,
    const _Float16* __restrict__ ea_csr, const float* __restrict__ we,
    const float* __restrict__ att, const float* __restrict__ bc,
    _Float16* __restrict__ out, int n) {
  constexpr int HC = H * 32;
  constexpr int NL = HC / 4;   // lanes per node (32 or 8)
  constexpr int NPB = 128 / NL;

  int tid = threadIdx.x;
  int ln = tid / NL, q = tid % NL;
  int c0 = 4 * q;
  int node = blockIdx.x * NPB + ln;
  if (node >= n) return;

  h2 w2[8][2];
#pragma unroll
  for (int k = 0; k < 8; k++) {
    float4 v = *(const float4*)&we[k * HC + c0];
    w2[k][0] = h2{(_Float16)v.x, (_Float16)v.y};
    w2[k][1] = h2{(_Float16)v.z, (_Float16)v.w};
  }
  const float LOG2E = 1.44269504088896f;
  float4 av = *(const float4*)&att[c0];
  h2 a0 = h2{(_Float16)(av.x * LOG2E), (_Float16)(av.y * LOG2E)};
  h2 a1 = h2{(_Float16)(av.z * LOG2E), (_Float16)(av.w * LOG2E)};
  h4 xrh = *(const h4*)&xr[(size_t)node * HC + c0];
  h2 xr0 = h2{xrh[0], xrh[1]}, xr1 = h2{xrh[2], xrh[3]};
  const h2 p2 = h2{(_Float16)0.2f, (_Float16)0.2f};

  float acc[4] = {0.f, 0.f, 0.f, 0.f};
  float s = 0.f;

  int start = row_ptr[node], end = row_ptr[node + 1];   // len >= 1 (self loop)
  int len = end - start;
  int pairs = (len + 1) >> 1;

  // prologue: load pair 0 (clamped)
  int j1 = (start + 1 < end) ? start + 1 : start;
  float m1 = (start + 1 < end) ? 1.f : 0.f;
  int s0 = csr_src[start], s1 = csr_src[j1];
  h8 e0 = *(const h8*)&ea_csr[(size_t)start * 8];
  h8 e1 = *(const h8*)&ea_csr[(size_t)j1 * 8];
  h4 x0 = *(const h4*)&xl[(size_t)s0 * HC + c0];
  h4 x1 = *(const h4*)&xl[(size_t)s1 * HC + c0];

#pragma unroll 2
  for (int p = 0; p < pairs; p++) {
    // ---- issue next pair's src/ea loads (clamped; unused garbage on last) ----
    int jn = start + 2 * (p + 1);
    int k0 = (jn < end) ? jn : start;
    int k1 = (jn + 1 < end) ? jn + 1 : k0;
    float nm1 = (jn + 1 < end) ? 1.f : 0.f;
    int ns0 = csr_src[k0], ns1 = csr_src[k1];
    h8 ne0 = *(const h8*)&ea_csr[(size_t)k0 * 8];
    h8 ne1 = *(const h8*)&ea_csr[(size_t)k1 * 8];

    // ---- logits for current pair (two independent chains) ----
    h2 t00 = h2{x0[0], x0[1]} + xr0;
    h2 t01 = h2{x0[2], x0[3]} + xr1;
    h2 t10 = h2{x1[0], x1[1]} + xr0;
    h2 t11 = h2{x1[2], x1[3]} + xr1;
#pragma unroll
    for (int k = 0; k < 8; k++) {
      h2 ev0 = h2{e0[k], e0[k]};
      h2 ev1 = h2{e1[k], e1[k]};
      t00 += ev0 * w2[k][0];
      t01 += ev0 * w2[k][1];
      t10 += ev1 * w2[k][0];
      t11 += ev1 * w2[k][1];
    }
    t00 = __builtin_elementwise_max(t00, t00 * p2);
    t01 = __builtin_elementwise_max(t01, t01 * p2);
    t10 = __builtin_elementwise_max(t10, t10 * p2);
    t11 = __builtin_elementwise_max(t11, t11 * p2);
    h2 pd0 = t00 * a0 + t01 * a1;
    h2 pd1 = t10 * a0 + t11 * a1;
    float part0 = (float)pd0[0] + (float)pd0[1];
    float part1 = (float)pd1[0] + (float)pd1[1];

    // ---- issue next pair's xl gathers before the reduce chain ----
    h4 nx0 = *(const h4*)&xl[(size_t)ns0 * HC + c0];
    h4 nx1 = *(const h4*)&xl[(size_t)ns1 * HC + c0];

    // ---- reduce across the 8 lanes of each head, exp, accumulate ----
    part0 += __shfl_xor(part0, 1, 64);
    part1 += __shfl_xor(part1, 1, 64);
    part0 += __shfl_xor(part0, 2, 64);
    part1 += __shfl_xor(part1, 2, 64);
    part0 += __shfl_xor(part0, 4, 64);
    part1 += __shfl_xor(part1, 4, 64);
    float pe0 = __builtin_amdgcn_exp2f(part0);
    float pe1 = __builtin_amdgcn_exp2f(part1) * m1;
    s += pe0 + pe1;
#pragma unroll
    for (int i = 0; i < 4; i++)
      acc[i] += pe0 * (float)x0[i] + pe1 * (float)x1[i];

    // ---- rotate pipeline registers (renamed away under unroll) ----
    s0 = ns0; s1 = ns1; e0 = ne0; e1 = ne1; x0 = nx0; x1 = nx1; m1 = nm1;
  }

  float inv = 1.f / (s + 1e-16f);
  h4 o;
#pragma unroll
  for (int i = 0; i < 4; i++) {
    float v = acc[i] * inv + bc[c0 + i];
    o[i] = (_Float16)(v > 0.f ? v : (__expf(v) - 1.f));   // elu
  }
  *(h4*)&out[(size_t)node * HC + c0] = o;
}

// ---------------------------------------------------------------- fused pooling + MLP
// block g: mean over graph g's node range -> fc1 (elu) -> fc2 -> out. gmean
// stays in LDS (pool2+fc fused, R10).
__global__ __launch_bounds__(256) void poolfc_kernel(const _Float16* __restrict__ h,
                                                     const int* __restrict__ gstart,
                                                     const float* __restrict__ w1,
                                                     const float* __restrict__ b1,
                                                     const float* __restrict__ w2,
                                                     const float* __restrict__ b2,
                                                     float* __restrict__ out) {
  __shared__ float red[256];
  __shared__ float g[32];
  __shared__ float a1[64];
  int gi = blockIdx.x;
  int t = threadIdx.x;
  int s = gstart[gi], e = gstart[gi + 1];
  int c = t & 31, rg = t >> 5;
  float acc = 0.f;
  for (int i = s + rg; i < e; i += 8) acc += (float)h[(size_t)i * 32 + c];
  red[t] = acc;
  __syncthreads();
  if (t < 128) red[t] += red[t + 128];
  __syncthreads();
  if (t < 64) red[t] += red[t + 64];
  __syncthreads();
  if (t < 32) g[t] = (red[t] + red[t + 32]) / fmaxf((float)(e - s), 1.f);
  __syncthreads();
  if (t < 64) {
    float v = b1[t];
    for (int k = 0; k < 32; k++) v += g[k] * w1[k * 64 + t];
    a1[t] = v > 0.f ? v : (__expf(v) - 1.f);
  }
  __syncthreads();
  if (t < 4) {
    float o = b2[t];
    for (int k = 0; k < 64; k++) o += a1[k] * w2[k * 4 + t];
    out[gi * 4 + t] = o;
  }
}

// ---------------------------------------------------------------- launch

extern "C" void kernel_launch(void* const* d_in, const int* in_sizes, int n_in,
                              void* d_out, int out_size, void* d_ws, size_t ws_size,
                              hipStream_t stream) {
  const float* x     = (const float*)d_in[0];
  const int*   ei    = (const int*)d_in[1];
  const float* eattr = (const float*)d_in[2];
  const int*   batch = (const int*)d_in[3];
  const float *wl1 = (const float*)d_in[4],  *bl1 = (const float*)d_in[5];
  const float *wr1 = (const float*)d_in[6],  *br1 = (const float*)d_in[7];
  const float *we1 = (const float*)d_in[8],  *at1 = (const float*)d_in[9];
  const float *bc1 = (const float*)d_in[10];
  const float *wl2 = (const float*)d_in[11], *bl2 = (const float*)d_in[12];
  const float *wr2 = (const float*)d_in[13], *br2 = (const float*)d_in[14];
  const float *we2 = (const float*)d_in[15], *at2 = (const float*)d_in[16];
  const float *bc2 = (const float*)d_in[17];
  const float *wl3 = (const float*)d_in[18], *bl3 = (const float*)d_in[19];
  const float *wr3 = (const float*)d_in[20], *br3 = (const float*)d_in[21];
  const float *we3 = (const float*)d_in[22], *at3 = (const float*)d_in[23];
  const float *bc3 = (const float*)d_in[24];
  const float *wf1 = (const float*)d_in[25], *bf1 = (const float*)d_in[26];
  const float *wf2 = (const float*)d_in[27], *bf2 = (const float*)d_in[28];

  int N = in_sizes[0] / 16;
  int E = in_sizes[1] / 2;
  const int* srcp = ei;
  const int* dstp = ei + E;
  int EA = E + N;             // CSR entries incl. self-loops
  int NB = (N + 511) / 512;   // scan blocks (<=1024)

  char* wsb = (char*)d_ws;
  size_t off = 0;
  auto alloc = [&](size_t bytes) -> char* {
    char* p = wsb + off;
    off += (bytes + 255) & ~(size_t)255;
    return p;
  };
  int*       cnt     = (int*)alloc((size_t)N * 4);
  int*       row_ptr = (int*)alloc((size_t)(N + 1) * 4);
  int*       fill    = (int*)alloc((size_t)N * 4);
  int*       bpart   = (int*)alloc((size_t)1024 * 4);
  int*       boff    = (int*)alloc((size_t)1024 * 4);
  int*       csr_src = (int*)alloc((size_t)EA * 4);
  _Float16*  ea_csr  = (_Float16*)alloc((size_t)EA * 8 * 2);
  _Float16*  xl      = (_Float16*)alloc((size_t)N * 128 * 2);
  _Float16*  xr      = (_Float16*)alloc((size_t)N * 128 * 2);
  _Float16*  h16     = (_Float16*)alloc((size_t)N * 128 * 2);
  _Float16*  h3      = (_Float16*)alloc((size_t)N * 32 * 2);
  int*       gstart  = (int*)alloc((size_t)(GNUM + 1) * 4);
  _Float16*  wp1l    = (_Float16*)alloc((size_t)32 * 128 * 2);
  _Float16*  wp1r    = (_Float16*)alloc((size_t)32 * 128 * 2);
  _Float16*  wp2l    = (_Float16*)alloc((size_t)128 * 128 * 2);
  _Float16*  wp2r    = (_Float16*)alloc((size_t)128 * 128 * 2);
  _Float16*  wp3l    = (_Float16*)alloc((size_t)128 * 32 * 2);
  _Float16*  wp3r    = (_Float16*)alloc((size_t)128 * 32 * 2);

  hipMemsetAsync(cnt, 0, (size_t)N * 4, stream);

  hist_kernel<<<(E + 255) / 256, 256, 0, stream>>>(dstp, cnt, E);
  scan_part_kernel<<<NB, 256, 0, stream>>>(cnt, bpart, N);
  scan_top_kernel<<<1, 1024, 0, stream>>>(bpart, boff, row_ptr, batch, gstart, NB, N);
  scan_write_kernel<<<NB, 256, 0, stream>>>(cnt, boff, row_ptr, fill, N);
  scatter_kernel<<<(E + 255) / 256, 256, 0, stream>>>(srcp, dstp, eattr, fill, csr_src, ea_csr, E);
  selfloop_kernel<<<(N * 8 + 255) / 256, 256, 0, stream>>>(row_ptr, csr_src, ea_csr, N);
  pack_all_kernel<<<dim3(8, 6), 256, 0, stream>>>(wl1, wp1l, wr1, wp1r,
                                                  wl2, wp2l, wr2, wp2r,
                                                  wl3, wp3l, wr3, wp3r);

  // layer 1: K=16 -> 128 (fp16 MFMA, K zero-padded to 32, f32 input)
  k1m16_kernel<128><<<dim3((N + 63) / 64, 2), 256, 0, stream>>>(
      x, wp1l, bl1, xl, wp1r, br1, xr, N);
  k2_kernel<4><<<(N + 3) / 4, 128, 0, stream>>>(xl, xr, row_ptr, csr_src, ea_csr,
                                                we1, at1, bc1, h16, N);
  // layer 2: K=128 -> 128 (fp16 MFMA)
  k1m_kernel<128, 128><<<dim3((N + 63) / 64, 2), 256, 0, stream>>>(
      h16, wp2l, bl2, xl, wp2r, br2, xr, N);
  k2_kernel<4><<<(N + 3) / 4, 128, 0, stream>>>(xl, xr, row_ptr, csr_src, ea_csr,
                                                we2, at2, bc2, h16, N);
  // layer 3: K=128 -> 32 (fp16 MFMA, single head)
  k1m_kernel<128, 32><<<dim3((N + 63) / 64, 2), 256, 0, stream>>>(
      h16, wp3l, bl3, xl, wp3r, br3, xr, N);
  k2_kernel<1><<<(N + 15) / 16, 128, 0, stream>>>(xl, xr, row_ptr, csr_src, ea_csr,
                                                  we3, at3, bc3, h3, N);

  poolfc_kernel<<<GNUM, 256, 0, stream>>>(h3, gstart, wf1, bf1, wf2, bf2, (float*)d_out);
}